// Round 5
// baseline (238.763 us; speedup 1.0000x reference)
//
#include <hip/hip_runtime.h>
#include <math.h>
#include <stdint.h>

#define NB   16
#define NPT  2048
#define NF   512
#define BI   128
#define BJ   128
#define KB   32
#define NTHR 512
#define NJT  (NPT / BJ)   // 16
#define NIT  (NPT / BI)   // 16
#define NKC  (NF / KB)    // 16

// LDS geometry (bytes). Col-group = 16 cols x 32 k fp16, internally
// [k-half][k-group 4][row 4][col 16], padded stride 1056 (=32B mod 128):
// staging writes 2-way-clean, tr-reads measured 0-conflict.
#define CGS    1056
#define PLANE  8448           // 8 col-groups (128 cols)
#define PLANE_H 4224
#define BUFB   33792          // fallback kernel: 4 planes of 8 cg
#define BPLANE 16896          // 16 col-groups (256 cols)
#define BUF2   50688          // Ahi(8448) Alo(8448) Bhi(16896) Blo(16896)

typedef _Float16 h4 __attribute__((ext_vector_type(4)));
typedef _Float16 h8 __attribute__((ext_vector_type(8)));
typedef float    f32x4 __attribute__((ext_vector_type(4)));

// ds_read_b64_tr_b16, NATURAL addressing (base + lane*8): 64 lanes cover a
// 512B [16k][16col] subtile; HW delivers lane l = col (l&15). [m156/m162]
#define TRR(dst, a) asm volatile("ds_read_b64_tr_b16 %0, %1" : "=v"(dst) : "v"(a))

// counted DS wait + scheduler fence (rule #18)
#define WAITK(N) asm volatile("s_waitcnt lgkmcnt(" #N ")" ::: "memory"); \
                 __builtin_amdgcn_sched_barrier(0);

__device__ __forceinline__ h8 cat(h4 a, h4 b) {
    return __builtin_shufflevector(a, b, 0, 1, 2, 3, 4, 5, 6, 7);
}

__device__ __forceinline__ void cvt4(const float4 v, h4& hi, h4& lo) {
    hi[0] = (_Float16)v.x; hi[1] = (_Float16)v.y;
    hi[2] = (_Float16)v.z; hi[3] = (_Float16)v.w;
    lo[0] = (_Float16)(v.x - (float)hi[0]);
    lo[1] = (_Float16)(v.y - (float)hi[1]);
    lo[2] = (_Float16)(v.z - (float)hi[2]);
    lo[3] = (_Float16)(v.w - (float)hi[3]);
}

__device__ __forceinline__ void cvt8(const float4 a, const float4 b, h8& hi, h8& lo) {
    hi[0] = (_Float16)a.x; hi[1] = (_Float16)a.y;
    hi[2] = (_Float16)a.z; hi[3] = (_Float16)a.w;
    hi[4] = (_Float16)b.x; hi[5] = (_Float16)b.y;
    hi[6] = (_Float16)b.z; hi[7] = (_Float16)b.w;
    lo[0] = (_Float16)(a.x - (float)hi[0]);
    lo[1] = (_Float16)(a.y - (float)hi[1]);
    lo[2] = (_Float16)(a.z - (float)hi[2]);
    lo[3] = (_Float16)(a.w - (float)hi[3]);
    lo[4] = (_Float16)(b.x - (float)hi[4]);
    lo[5] = (_Float16)(b.y - (float)hi[5]);
    lo[6] = (_Float16)(b.z - (float)hi[6]);
    lo[7] = (_Float16)(b.w - (float)hi[7]);
}

__device__ __forceinline__ int hoffB(int f, int n8) {
    // byte offset within a plane for an 8-col chunk (f row, cols n8*8..+7)
    return (n8 >> 1) * CGS + (f >> 4) * 512 + ((f >> 2) & 3) * 128
         + (f & 3) * 32 + (n8 & 1) * 16;
}

// ---------------------------------------------------------------------------
// Kernel A (main path): 128i x 256j logits tile, fp16 hi/lo split MFMA
// (3 terms), m4 x n4 register blocking. Round-5: incremental tr-read issue
// with counted-lgkmcnt ladder (all waits <= 8, 4-bit field), staging writes
// hoisted under m3's MFMAs. Grid (16 b, 8 jt, 2 ihalf), 512 thr.
// ---------------------------------------------------------------------------
__global__ __launch_bounds__(NTHR, 2)
void attn_state_kernel(const float* __restrict__ target,
                       const float* __restrict__ fsource,
                       const float* __restrict__ ftarget,
                       float* __restrict__ stw)   // [5][16*2*2048]
{
    const int b    = blockIdx.x;
    const int jt   = blockIdx.y;          // 0..7  (256-wide j tiles)
    const int ih   = blockIdx.z;          // 0..1  (i halves of 1024)
    const int j0   = jt * 256;
    const int tid  = threadIdx.x;
    const int lane = tid & 63;
    const int wave = tid >> 6;
    const int wi   = wave >> 2;           // 0..1: rows [wi*64, wi*64+64)
    const int wj   = wave & 3;            // 0..3: cols [wj*64, wj*64+64)
    const int lg   = lane >> 4;
    const int lr   = lane & 15;

    __shared__ __align__(16) unsigned char TIL[2][BUF2];
    __shared__ float  tgts[3][BI];
    __shared__ float  redM[2][256];
    __shared__ float4 redS[2][256];

    const uint32_t tilesBase = (uint32_t)(uintptr_t)&TIL[0][0];
    const uint32_t trLane    = (uint32_t)(lane * 8);
    const size_t   fbase     = (size_t)b * NF * NPT;

    // staging assignment: A chunk = tid (32f x 16 chunks); B chunks tid, tid+512
    const int fA  = tid >> 4,  n8A  = tid & 15;
    const int fB0 = tid >> 5,  n8B  = tid & 31;
    const int fB1 = (tid + 512) >> 5;
    const int offA  = hoffB(fA, n8A);
    const int offB0 = hoffB(fB0, n8B);
    const int offB1 = hoffB(fB1, n8B);

    float Mrun[4], Zrun[4], Yrun[4][3];
    #pragma unroll
    for (int n = 0; n < 4; ++n) {
        Mrun[n] = -3.0e38f; Zrun[n] = 0.0f;
        Yrun[n][0] = 0.0f; Yrun[n][1] = 0.0f; Yrun[n][2] = 0.0f;
    }

#define RD_B(n) TRR(tb[n][0][0], bB + (n) * CGS); \
                TRR(tb[n][0][1], bB + (n) * CGS + 512); \
                TRR(tb[n][1][0], bB + (n) * CGS + BPLANE); \
                TRR(tb[n][1][1], bB + (n) * CGS + BPLANE + 512);
#define RD_A(m) TRR(ta[m][0][0], aB + (m) * CGS); \
                TRR(ta[m][0][1], aB + (m) * CGS + 512); \
                TRR(ta[m][1][0], aB + (m) * CGS + PLANE); \
                TRR(ta[m][1][1], aB + (m) * CGS + PLANE + 512);
#define BBLD(n) Bh[n] = cat(tb[n][0][0], tb[n][0][1]); \
                Bl[n] = cat(tb[n][1][0], tb[n][1][1]);
#define ABLD(m) Ah = cat(ta[m][0][0], ta[m][0][1]); \
                Al = cat(ta[m][1][0], ta[m][1][1]);
#define MM3(M, N) \
    acc[M][N] = __builtin_amdgcn_mfma_f32_16x16x32_f16(Ah, Bh[N], acc[M][N], 0, 0, 0); \
    acc[M][N] = __builtin_amdgcn_mfma_f32_16x16x32_f16(Ah, Bl[N], acc[M][N], 0, 0, 0); \
    acc[M][N] = __builtin_amdgcn_mfma_f32_16x16x32_f16(Al, Bh[N], acc[M][N], 0, 0, 0);

    for (int it = 0; it < 8; ++it) {
        const int i0 = ih * 1024 + it * BI;

        const float* pA  = ftarget + fbase + (size_t)fA  * NPT + i0 + n8A * 8;
        const float* pB0 = fsource + fbase + (size_t)fB0 * NPT + j0 + n8B * 8;
        const float* pB1 = fsource + fbase + (size_t)fB1 * NPT + j0 + n8B * 8;

        // ---- prologue: stage chunk 0 -> buf0, load target coords ----
        {
            float4 a0  = *(const float4*)(pA);
            float4 a1  = *(const float4*)(pA + 4);
            float4 b00 = *(const float4*)(pB0);
            float4 b01 = *(const float4*)(pB0 + 4);
            float4 b10 = *(const float4*)(pB1);
            float4 b11 = *(const float4*)(pB1 + 4);
            if (tid < BI) {
                const float* tp = target + ((size_t)b * NPT + i0 + tid) * 3;
                tgts[0][tid] = tp[0]; tgts[1][tid] = tp[1]; tgts[2][tid] = tp[2];
            }
            unsigned char* bp = (unsigned char*)&TIL[0][0];
            h8 hi, lo;
            cvt8(a0, a1, hi, lo);
            *(h8*)(bp + offA) = hi;  *(h8*)(bp + PLANE + offA) = lo;
            cvt8(b00, b01, hi, lo);
            *(h8*)(bp + 2 * PLANE + offB0) = hi;  *(h8*)(bp + 2 * PLANE + BPLANE + offB0) = lo;
            cvt8(b10, b11, hi, lo);
            *(h8*)(bp + 2 * PLANE + offB1) = hi;  *(h8*)(bp + 2 * PLANE + BPLANE + offB1) = lo;
        }
        __syncthreads();

        f32x4 acc[4][4];
        #pragma unroll
        for (int m = 0; m < 4; ++m)
            #pragma unroll
            for (int n = 0; n < 4; ++n)
                acc[m][n] = (f32x4){0.0f, 0.0f, 0.0f, 0.0f};

        // ---- main kc loop (kc = 0..14): prefetch + pipelined compute ----
        for (int kc = 0; kc < NKC - 1; ++kc) {
            const int buf = kc & 1;
            const size_t ko = (size_t)(kc + 1) * KB * NPT;
            float4 ga0  = *(const float4*)(pA + ko);
            float4 ga1  = *(const float4*)(pA + ko + 4);
            float4 gb00 = *(const float4*)(pB0 + ko);
            float4 gb01 = *(const float4*)(pB0 + ko + 4);
            float4 gb10 = *(const float4*)(pB1 + ko);
            float4 gb11 = *(const float4*)(pB1 + ko + 4);

            const uint32_t bb = tilesBase + (uint32_t)buf * BUF2;
            const uint32_t aB = bb + (uint32_t)(wi * 4) * CGS + trLane;
            const uint32_t bB = bb + 2u * PLANE + (uint32_t)(wj * 4) * CGS + trLane;
            h4 ta[4][2][2], tb[4][2][2];
            h8 Bh[4], Bl[4], Ah, Al;

            __builtin_amdgcn_s_setprio(1);
            RD_B(0) RD_A(0) RD_B(1)          // out: 12
            WAITK(4)  BBLD(0) ABLD(0) MM3(0, 0)
            RD_B(2)                          // out: B1,B2 -> wait B1
            WAITK(4)  BBLD(1) MM3(0, 1)
            RD_B(3)
            WAITK(4)  BBLD(2) MM3(0, 2)
            RD_A(1)
            WAITK(4)  BBLD(3) MM3(0, 3)
            RD_A(2)
            WAITK(4)  ABLD(1) MM3(1, 0) MM3(1, 1) MM3(1, 2) MM3(1, 3)
            RD_A(3)
            WAITK(4)  ABLD(2) MM3(2, 0) MM3(2, 1) MM3(2, 2) MM3(2, 3)
            __builtin_amdgcn_s_setprio(0);
            // stage kc+1 into buf^1 (loads issued ~1500 cy ago; writes drain
            // under m3's MFMAs). 6 ds_writes outstanding at the next wait.
            {
                unsigned char* bp = (unsigned char*)&TIL[0][0] + (buf ^ 1) * BUF2;
                h8 hi, lo;
                cvt8(ga0, ga1, hi, lo);
                *(h8*)(bp + offA) = hi;  *(h8*)(bp + PLANE + offA) = lo;
                cvt8(gb00, gb01, hi, lo);
                *(h8*)(bp + 2 * PLANE + offB0) = hi;  *(h8*)(bp + 2 * PLANE + BPLANE + offB0) = lo;
                cvt8(gb10, gb11, hi, lo);
                *(h8*)(bp + 2 * PLANE + offB1) = hi;  *(h8*)(bp + 2 * PLANE + BPLANE + offB1) = lo;
            }
            __builtin_amdgcn_s_setprio(1);
            WAITK(6)  ABLD(3) MM3(3, 0) MM3(3, 1) MM3(3, 2) MM3(3, 3)
            __builtin_amdgcn_s_setprio(0);
            __syncthreads();
        }

        // ---- tail kc = NKC-1: no prefetch, no staging ----
        {
            const uint32_t bb = tilesBase + (uint32_t)((NKC - 1) & 1) * BUF2;
            const uint32_t aB = bb + (uint32_t)(wi * 4) * CGS + trLane;
            const uint32_t bB = bb + 2u * PLANE + (uint32_t)(wj * 4) * CGS + trLane;
            h4 ta[4][2][2], tb[4][2][2];
            h8 Bh[4], Bl[4], Ah, Al;

            __builtin_amdgcn_s_setprio(1);
            RD_B(0) RD_A(0) RD_B(1)
            WAITK(4)  BBLD(0) ABLD(0) MM3(0, 0)
            RD_B(2)
            WAITK(4)  BBLD(1) MM3(0, 1)
            RD_B(3)
            WAITK(4)  BBLD(2) MM3(0, 2)
            RD_A(1)
            WAITK(4)  BBLD(3) MM3(0, 3)
            RD_A(2)
            WAITK(4)  ABLD(1) MM3(1, 0) MM3(1, 1) MM3(1, 2) MM3(1, 3)
            RD_A(3)
            WAITK(4)  ABLD(2) MM3(2, 0) MM3(2, 1) MM3(2, 2) MM3(2, 3)
            WAITK(0)  ABLD(3) MM3(3, 0) MM3(3, 1) MM3(3, 2) MM3(3, 3)
            __builtin_amdgcn_s_setprio(0);
        }

        // ---- online softmax update for this i-tile ----
        // D layout: col j = wj*64 + n*16 + lr, row i = wi*64 + m*16 + lg*4 + r
        #pragma unroll
        for (int n = 0; n < 4; ++n) {
            float m = acc[0][n][0];
            #pragma unroll
            for (int mm = 0; mm < 4; ++mm)
                #pragma unroll
                for (int r = 0; r < 4; ++r)
                    m = fmaxf(m, acc[mm][n][r]);
            m = fmaxf(m, __shfl_xor(m, 16));
            m = fmaxf(m, __shfl_xor(m, 32));
            if (lane < 16) redM[wi][wj * 64 + n * 16 + lr] = m;
        }
        __syncthreads();
        float mnew[4];
        #pragma unroll
        for (int n = 0; n < 4; ++n) {
            const int col = wj * 64 + n * 16 + lr;
            mnew[n] = fmaxf(Mrun[n], fmaxf(redM[0][col], redM[1][col]));
        }

        float z[4] = {0, 0, 0, 0}, y[4][3] = {{0,0,0},{0,0,0},{0,0,0},{0,0,0}};
        #pragma unroll
        for (int mm = 0; mm < 4; ++mm)
            #pragma unroll
            for (int r = 0; r < 4; ++r) {
                const int iL = wi * 64 + mm * 16 + lg * 4 + r;
                const float t0 = tgts[0][iL], t1 = tgts[1][iL], t2 = tgts[2][iL];
                #pragma unroll
                for (int n = 0; n < 4; ++n) {
                    const float e = __expf(acc[mm][n][r] - mnew[n]);
                    z[n] += e;
                    y[n][0] = fmaf(e, t0, y[n][0]);
                    y[n][1] = fmaf(e, t1, y[n][1]);
                    y[n][2] = fmaf(e, t2, y[n][2]);
                }
            }
        #pragma unroll
        for (int n = 0; n < 4; ++n) {
            #pragma unroll
            for (int off = 16; off <= 32; off <<= 1) {
                z[n]    += __shfl_xor(z[n], off);
                y[n][0] += __shfl_xor(y[n][0], off);
                y[n][1] += __shfl_xor(y[n][1], off);
                y[n][2] += __shfl_xor(y[n][2], off);
            }
            if (lane < 16)
                redS[wi][wj * 64 + n * 16 + lr] = make_float4(z[n], y[n][0], y[n][1], y[n][2]);
        }
        __syncthreads();
        #pragma unroll
        for (int n = 0; n < 4; ++n) {
            const int col = wj * 64 + n * 16 + lr;
            const float4 s0 = redS[0][col], s1 = redS[1][col];
            const float sc = __expf(Mrun[n] - mnew[n]);
            Zrun[n]    = Zrun[n]    * sc + s0.x + s1.x;
            Yrun[n][0] = Yrun[n][0] * sc + s0.y + s1.y;
            Yrun[n][1] = Yrun[n][1] * sc + s0.z + s1.z;
            Yrun[n][2] = Yrun[n][2] * sc + s0.w + s1.w;
            Mrun[n] = mnew[n];
        }
        __syncthreads();   // protect redM/redS & tiles before next it's staging
    }

    // ---- write per-column state ----
    if (wi == 0 && lane < 16) {
        #pragma unroll
        for (int n = 0; n < 4; ++n) {
            const int j   = j0 + wj * 64 + n * 16 + lr;
            const int idx = (b * 2 + ih) * NPT + j;
            stw[0 * (NB * 2 * NPT) + idx] = Mrun[n];
            stw[1 * (NB * 2 * NPT) + idx] = Zrun[n];
            stw[2 * (NB * 2 * NPT) + idx] = Yrun[n][0];
            stw[3 * (NB * 2 * NPT) + idx] = Yrun[n][1];
            stw[4 * (NB * 2 * NPT) + idx] = Yrun[n][2];
        }
    }
#undef RD_B
#undef RD_A
#undef BBLD
#undef ABLD
#undef MM3
}

// ---------------------------------------------------------------------------
// Combine kernel: merge the two i-half softmax states per column, compute
// pred, then per-(b, 128-j-chunk) partial sums (15 values).
// ---------------------------------------------------------------------------
__global__ void combine_kernel(const float* __restrict__ source,
                               const float* __restrict__ stw,
                               float* __restrict__ partials)
{
    const int b   = blockIdx.x;
    const int jc  = blockIdx.y;     // 0..15
    const int tid = threadIdx.x;    // 128
    const int lane = tid & 63, wv = tid >> 6;
    const int j = jc * BJ + tid;
    const int SP = NB * 2 * NPT;
    const int i0 = (b * 2 + 0) * NPT + j;
    const int i1 = (b * 2 + 1) * NPT + j;

    __shared__ float fin2[2][15];

    const float ma = stw[i0],            mb = stw[i1];
    const float za = stw[SP + i0],       zb = stw[SP + i1];
    const float ms = fmaxf(ma, mb);
    const float sa = __expf(ma - ms), sb = __expf(mb - ms);
    const float z  = za * sa + zb * sb;
    const float iz = 1.0f / z;
    const float p0 = (stw[2 * SP + i0] * sa + stw[2 * SP + i1] * sb) * iz;
    const float p1 = (stw[3 * SP + i0] * sa + stw[3 * SP + i1] * sb) * iz;
    const float p2 = (stw[4 * SP + i0] * sa + stw[4 * SP + i1] * sb) * iz;

    const float* sp = source + ((size_t)b * NPT + j) * 3;
    const float s0 = sp[0], s1 = sp[1], s2 = sp[2];

    float v[15];
    v[0] = s0; v[1] = s1; v[2] = s2;
    v[3] = p0; v[4] = p1; v[5] = p2;
    v[6]  = s0 * p0; v[7]  = s0 * p1; v[8]  = s0 * p2;
    v[9]  = s1 * p0; v[10] = s1 * p1; v[11] = s1 * p2;
    v[12] = s2 * p0; v[13] = s2 * p1; v[14] = s2 * p2;

    #pragma unroll
    for (int q = 0; q < 15; ++q)
        #pragma unroll
        for (int off = 32; off > 0; off >>= 1)
            v[q] += __shfl_down(v[q], off);
    if (lane == 0) {
        #pragma unroll
        for (int q = 0; q < 15; ++q) fin2[wv][q] = v[q];
    }
    __syncthreads();
    if (tid == 0) {
        float* o = partials + (((size_t)b << 4) + jc) * 16;
        #pragma unroll
        for (int q = 0; q < 15; ++q) o[q] = fin2[0][q] + fin2[1][q];
    }
}

// ---------------------------------------------------------------------------
// Fallback kernel (round-3, proven): used only if ws_size is too small.
// ---------------------------------------------------------------------------
__global__ __launch_bounds__(NTHR, 2)
void attn_partials_kernel(const float* __restrict__ source,
                          const float* __restrict__ target,
                          const float* __restrict__ fsource,
                          const float* __restrict__ ftarget,
                          float* __restrict__ partials)
{
    const int b    = blockIdx.x;
    const int jt   = blockIdx.y;
    const int j0   = jt * BJ;
    const int tid  = threadIdx.x;
    const int lane = tid & 63;
    const int wave = tid >> 6;
    const int wi   = wave >> 2;
    const int wj   = wave & 3;
    const int lg   = lane >> 4;
    const int lr   = lane & 15;

    __shared__ __align__(16) _Float16 TILES[2][4][PLANE_H];
    __shared__ float  tgts[3][BI];
    __shared__ float  redM[2][BJ];
    __shared__ float4 redS[2][BJ];
    __shared__ float  predL[3][BJ];
    __shared__ float  fin[8][15];

    const uint32_t tilesBase = (uint32_t)(uintptr_t)&TILES[0][0][0];
    const uint32_t trLane    = (uint32_t)(lane * 8);
    const size_t fbase = (size_t)b * NF * NPT;

    float Mrun[2], Zrun[2], Yrun[2][3];
    #pragma unroll
    for (int n = 0; n < 2; ++n) {
        Mrun[n] = -3.0e38f; Zrun[n] = 0.0f;
        Yrun[n][0] = 0.0f; Yrun[n][1] = 0.0f; Yrun[n][2] = 0.0f;
    }

    float4 gA[2], gB[2];

    for (int it = 0; it < NIT; ++it) {
        const int i0 = it * BI;
        #pragma unroll
        for (int p = 0; p < 2; ++p) {
            const int q = tid + p * NTHR;
            const int f = q >> 5, i4 = q & 31;
            gA[p] = *(const float4*)(ftarget + fbase + (size_t)f * NPT + i0 + i4 * 4);
            gB[p] = *(const float4*)(fsource + fbase + (size_t)f * NPT + j0 + i4 * 4);
        }
        if (tid < BI) {
            const float* tp = target + ((size_t)b * NPT + i0 + tid) * 3;
            tgts[0][tid] = tp[0]; tgts[1][tid] = tp[1]; tgts[2][tid] = tp[2];
        }
        #pragma unroll
        for (int p = 0; p < 2; ++p) {
            const int q = tid + p * NTHR;
            const int f = q >> 5, i4 = q & 31;
            const int hoff = (i4 >> 2) * 528 + (f >> 4) * 256 + ((f >> 2) & 3) * 64
                           + (f & 3) * 16 + (i4 & 3) * 4;
            _Float16* bp = &TILES[0][0][0];
            h4 hi, lo;
            cvt4(gA[p], hi, lo);
            *(h4*)(bp + hoff)               = hi;
            *(h4*)(bp + PLANE_H + hoff)     = lo;
            cvt4(gB[p], hi, lo);
            *(h4*)(bp + 2 * PLANE_H + hoff) = hi;
            *(h4*)(bp + 3 * PLANE_H + hoff) = lo;
        }
        __syncthreads();

        f32x4 acc[4][2];
        #pragma unroll
        for (int m = 0; m < 4; ++m)
            #pragma unroll
            for (int n = 0; n < 2; ++n)
                acc[m][n] = (f32x4){0.0f, 0.0f, 0.0f, 0.0f};

        for (int kc = 0; kc < NKC; ++kc) {
            const int buf = kc & 1;
            if (kc + 1 < NKC) {
                #pragma unroll
                for (int p = 0; p < 2; ++p) {
                    const int q = tid + p * NTHR;
                    const int f = q >> 5, i4 = q & 31;
                    const size_t row = (size_t)((kc + 1) * KB + f) * NPT;
                    gA[p] = *(const float4*)(ftarget + fbase + row + i0 + i4 * 4);
                    gB[p] = *(const float4*)(fsource + fbase + row + j0 + i4 * 4);
                }
            }
            const uint32_t bufB = tilesBase + (uint32_t)buf * BUFB;
            const uint32_t aHi  = bufB + (uint32_t)(wi * 4) * CGS + trLane;
            const uint32_t bHi  = bufB + 2u * PLANE + (uint32_t)(wj * 2) * CGS + trLane;
            h4 ta[4][2][2], tb[2][2][2];
            #pragma unroll
            for (int n = 0; n < 2; ++n) {
                TRR(tb[n][0][0], bHi + n * CGS);
                TRR(tb[n][0][1], bHi + n * CGS + 512);
                TRR(tb[n][1][0], bHi + n * CGS + PLANE);
                TRR(tb[n][1][1], bHi + n * CGS + PLANE + 512);
            }
            #pragma unroll
            for (int m = 0; m < 4; ++m) {
                TRR(ta[m][0][0], aHi + m * CGS);
                TRR(ta[m][0][1], aHi + m * CGS + 512);
                TRR(ta[m][1][0], aHi + m * CGS + PLANE);
                TRR(ta[m][1][1], aHi + m * CGS + PLANE + 512);
            }
            asm volatile("s_waitcnt lgkmcnt(0)" ::: "memory");
            __builtin_amdgcn_sched_barrier(0);

            h8 Bh[2], Bl[2];
            #pragma unroll
            for (int n = 0; n < 2; ++n) {
                Bh[n] = cat(tb[n][0][0], tb[n][0][1]);
                Bl[n] = cat(tb[n][1][0], tb[n][1][1]);
            }
            #pragma unroll
            for (int m = 0; m < 4; ++m) {
                const h8 Ah = cat(ta[m][0][0], ta[m][0][1]);
                const h8 Al = cat(ta[m][1][0], ta[m][1][1]);
                #pragma unroll
                for (int n = 0; n < 2; ++n) {
                    acc[m][n] = __builtin_amdgcn_mfma_f32_16x16x32_f16(Ah, Bh[n], acc[m][n], 0, 0, 0);
                    acc[m][n] = __builtin_amdgcn_mfma_f32_16x16x32_f16(Ah, Bl[n], acc[m][n], 0, 0, 0);
                    acc[m][n] = __builtin_amdgcn_mfma_f32_16x16x32_f16(Al, Bh[n], acc[m][n], 0, 0, 0);
                }
            }
            if (kc + 1 < NKC) {
                #pragma unroll
                for (int p = 0; p < 2; ++p) {
                    const int q = tid + p * NTHR;
                    const int f = q >> 5, i4 = q & 31;
                    const int hoff = (i4 >> 2) * 528 + (f >> 4) * 256 + ((f >> 2) & 3) * 64
                                   + (f & 3) * 16 + (i4 & 3) * 4;
                    _Float16* bp = &TILES[buf ^ 1][0][0];
                    h4 hi, lo;
                    cvt4(gA[p], hi, lo);
                    *(h4*)(bp + hoff)               = hi;
                    *(h4*)(bp + PLANE_H + hoff)     = lo;
                    cvt4(gB[p], hi, lo);
                    *(h4*)(bp + 2 * PLANE_H + hoff) = hi;
                    *(h4*)(bp + 3 * PLANE_H + hoff) = lo;
                }
                __syncthreads();
            }
        }

        #pragma unroll
        for (int n = 0; n < 2; ++n) {
            float m = acc[0][n][0];
            #pragma unroll
            for (int mm = 0; mm < 4; ++mm)
                #pragma unroll
                for (int r = 0; r < 4; ++r)
                    m = fmaxf(m, acc[mm][n][r]);
            m = fmaxf(m, __shfl_xor(m, 16));
            m = fmaxf(m, __shfl_xor(m, 32));
            if (lane < 16) redM[wi][wj * 32 + n * 16 + lr] = m;
        }
        __syncthreads();
        float mnew[2];
        #pragma unroll
        for (int n = 0; n < 2; ++n) {
            const int col = wj * 32 + n * 16 + lr;
            mnew[n] = fmaxf(Mrun[n], fmaxf(redM[0][col], redM[1][col]));
        }

        float z[2] = {0.0f, 0.0f}, y[2][3] = {{0, 0, 0}, {0, 0, 0}};
        #pragma unroll
        for (int mm = 0; mm < 4; ++mm)
            #pragma unroll
            for (int r = 0; r < 4; ++r) {
                const int iL = wi * 64 + mm * 16 + lg * 4 + r;
                const float t0 = tgts[0][iL], t1 = tgts[1][iL], t2 = tgts[2][iL];
                #pragma unroll
                for (int n = 0; n < 2; ++n) {
                    const float e = __expf(acc[mm][n][r] - mnew[n]);
                    z[n] += e;
                    y[n][0] = fmaf(e, t0, y[n][0]);
                    y[n][1] = fmaf(e, t1, y[n][1]);
                    y[n][2] = fmaf(e, t2, y[n][2]);
                }
            }
        #pragma unroll
        for (int n = 0; n < 2; ++n) {
            #pragma unroll
            for (int off = 16; off <= 32; off <<= 1) {
                z[n]    += __shfl_xor(z[n], off);
                y[n][0] += __shfl_xor(y[n][0], off);
                y[n][1] += __shfl_xor(y[n][1], off);
                y[n][2] += __shfl_xor(y[n][2], off);
            }
            if (lane < 16)
                redS[wi][wj * 32 + n * 16 + lr] = make_float4(z[n], y[n][0], y[n][1], y[n][2]);
        }
        __syncthreads();
        #pragma unroll
        for (int n = 0; n < 2; ++n) {
            const int col = wj * 32 + n * 16 + lr;
            const float4 s0 = redS[0][col], s1 = redS[1][col];
            const float sc = __expf(Mrun[n] - mnew[n]);
            Zrun[n]    = Zrun[n]    * sc + s0.x + s1.x;
            Yrun[n][0] = Yrun[n][0] * sc + s0.y + s1.y;
            Yrun[n][1] = Yrun[n][1] * sc + s0.z + s1.z;
            Yrun[n][2] = Yrun[n][2] * sc + s0.w + s1.w;
            Mrun[n] = mnew[n];
        }
    }

    if (lane < 16) {
        #pragma unroll
        for (int n = 0; n < 2; ++n) {
            const int col = wj * 32 + n * 16 + lr;
            const float iz = 1.0f / Zrun[n];
            predL[0][col] = Yrun[n][0] * iz;
            predL[1][col] = Yrun[n][1] * iz;
            predL[2][col] = Yrun[n][2] * iz;
        }
    }
    __syncthreads();

    float v[15];
    #pragma unroll
    for (int q = 0; q < 15; ++q) v[q] = 0.0f;
    if (tid < BJ) {
        const float p0 = predL[0][tid], p1 = predL[1][tid], p2 = predL[2][tid];
        const float* sp = source + ((size_t)b * NPT + j0 + tid) * 3;
        const float s0 = sp[0], s1 = sp[1], s2 = sp[2];
        v[0] = s0; v[1] = s1; v[2] = s2;
        v[3] = p0; v[4] = p1; v[5] = p2;
        v[6]  = s0 * p0; v[7]  = s0 * p1; v[8]  = s0 * p2;
        v[9]  = s1 * p0; v[10] = s1 * p1; v[11] = s1 * p2;
        v[12] = s2 * p0; v[13] = s2 * p1; v[14] = s2 * p2;
    }
    #pragma unroll
    for (int q = 0; q < 15; ++q)
        #pragma unroll
        for (int off = 32; off > 0; off >>= 1)
            v[q] += __shfl_down(v[q], off);
    if (lane == 0) {
        #pragma unroll
        for (int q = 0; q < 15; ++q) fin[wave][q] = v[q];
    }
    __syncthreads();
    if (tid == 0) {
        float* o = partials + (((size_t)b << 4) + jt) * 16;
        #pragma unroll
        for (int q = 0; q < 15; ++q) {
            float s = 0.0f;
            #pragma unroll
            for (int w = 0; w < 8; ++w) s += fin[w][q];
            o[q] = s;
        }
    }
}

// ---------------------------------------------------------------------------
// Kernel B: per-batch 3x3 covariance -> SVD (Jacobi on S^T S) -> R, t
// ---------------------------------------------------------------------------
__device__ inline void jrot(float A[3][3], float V[3][3], int p, int q)
{
    const float apq = A[p][q];
    if (fabsf(apq) < 1e-28f) return;
    const float tau = (A[q][q] - A[p][p]) / (2.0f * apq);
    const float t   = (tau >= 0.0f ? 1.0f : -1.0f) / (fabsf(tau) + sqrtf(1.0f + tau * tau));
    const float c   = rsqrtf(1.0f + t * t);
    const float s   = t * c;
    const float app = A[p][p], aqq = A[q][q];
    A[p][p] = app - t * apq;
    A[q][q] = aqq + t * apq;
    A[p][q] = 0.0f; A[q][p] = 0.0f;
    const int r = 3 - p - q;
    const float arp = A[r][p], arq = A[r][q];
    A[r][p] = c * arp - s * arq; A[p][r] = A[r][p];
    A[r][q] = s * arp + c * arq; A[q][r] = A[r][q];
    #pragma unroll
    for (int rr = 0; rr < 3; ++rr) {
        const float vrp = V[rr][p], vrq = V[rr][q];
        V[rr][p] = c * vrp - s * vrq;
        V[rr][q] = s * vrp + c * vrq;
    }
}

__global__ void svd_finalize_kernel(const float* __restrict__ partials,
                                    float* __restrict__ out)
{
    const int b = threadIdx.x;
    if (b >= NB) return;

    float srcS[3] = {0, 0, 0}, predS[3] = {0, 0, 0}, SP[9] = {0, 0, 0, 0, 0, 0, 0, 0, 0};
    for (int p = 0; p < NJT; ++p) {
        const float* vv = partials + (((size_t)b << 4) + p) * 16;
        srcS[0] += vv[0]; srcS[1] += vv[1]; srcS[2] += vv[2];
        predS[0] += vv[3]; predS[1] += vv[4]; predS[2] += vv[5];
        #pragma unroll
        for (int q = 0; q < 9; ++q) SP[q] += vv[6 + q];
    }

    const float invN = 1.0f / (float)NPT;
    float ms[3], mt[3];
    #pragma unroll
    for (int c = 0; c < 3; ++c) { ms[c] = srcS[c] * invN; mt[c] = predS[c] * invN; }

    float S[3][3];
    #pragma unroll
    for (int c = 0; c < 3; ++c)
        #pragma unroll
        for (int d = 0; d < 3; ++d)
            S[c][d] = SP[c * 3 + d] - srcS[c] * predS[d] * invN;

    float A[3][3];
    #pragma unroll
    for (int i = 0; i < 3; ++i)
        #pragma unroll
        for (int j = 0; j < 3; ++j)
            A[i][j] = S[0][i] * S[0][j] + S[1][i] * S[1][j] + S[2][i] * S[2][j];

    float V[3][3] = {{1, 0, 0}, {0, 1, 0}, {0, 0, 1}};
    for (int sweep = 0; sweep < 12; ++sweep) {
        jrot(A, V, 0, 1);
        jrot(A, V, 0, 2);
        jrot(A, V, 1, 2);
    }

    float lam[3] = {A[0][0], A[1][1], A[2][2]};
    for (int i = 0; i < 2; ++i) {
        int mx = i;
        for (int j = i + 1; j < 3; ++j) if (lam[j] > lam[mx]) mx = j;
        if (mx != i) {
            const float tl = lam[i]; lam[i] = lam[mx]; lam[mx] = tl;
            #pragma unroll
            for (int r = 0; r < 3; ++r) {
                const float tv = V[r][i]; V[r][i] = V[r][mx]; V[r][mx] = tv;
            }
        }
    }

    float w0[3], w1[3], u1[3], u2[3], u3[3];
    #pragma unroll
    for (int r = 0; r < 3; ++r) {
        w0[r] = S[r][0] * V[0][0] + S[r][1] * V[1][0] + S[r][2] * V[2][0];
        w1[r] = S[r][0] * V[0][1] + S[r][1] * V[1][1] + S[r][2] * V[2][1];
    }
    const float n1 = sqrtf(w0[0] * w0[0] + w0[1] * w0[1] + w0[2] * w0[2]) + 1e-30f;
    #pragma unroll
    for (int r = 0; r < 3; ++r) u1[r] = w0[r] / n1;
    const float d01 = u1[0] * w1[0] + u1[1] * w1[1] + u1[2] * w1[2];
    #pragma unroll
    for (int r = 0; r < 3; ++r) u2[r] = w1[r] - d01 * u1[r];
    const float n2 = sqrtf(u2[0] * u2[0] + u2[1] * u2[1] + u2[2] * u2[2]) + 1e-30f;
    #pragma unroll
    for (int r = 0; r < 3; ++r) u2[r] /= n2;
    u3[0] = u1[1] * u2[2] - u1[2] * u2[1];
    u3[1] = u1[2] * u2[0] - u1[0] * u2[2];
    u3[2] = u1[0] * u2[1] - u1[1] * u2[0];

    const float detV =
        V[0][0] * (V[1][1] * V[2][2] - V[1][2] * V[2][1]) -
        V[0][1] * (V[1][0] * V[2][2] - V[1][2] * V[2][0]) +
        V[0][2] * (V[1][0] * V[2][1] - V[1][1] * V[2][0]);

    float R[3][3];
    #pragma unroll
    for (int r = 0; r < 3; ++r)
        #pragma unroll
        for (int c = 0; c < 3; ++c)
            R[r][c] = V[r][0] * u1[c] + V[r][1] * u2[c] + detV * V[r][2] * u3[c];

    #pragma unroll
    for (int r = 0; r < 3; ++r)
        #pragma unroll
        for (int c = 0; c < 3; ++c)
            out[b * 9 + r * 3 + c] = R[r][c];

    #pragma unroll
    for (int r = 0; r < 3; ++r) {
        const float tr = mt[r] - (R[r][0] * ms[0] + R[r][1] * ms[1] + R[r][2] * ms[2]);
        out[NB * 9 + b * 3 + r] = tr;
    }
}

extern "C" void kernel_launch(void* const* d_in, const int* in_sizes, int n_in,
                              void* d_out, int out_size, void* d_ws, size_t ws_size,
                              hipStream_t stream)
{
    const float* source  = (const float*)d_in[0];
    const float* target  = (const float*)d_in[1];
    const float* fsource = (const float*)d_in[2];
    const float* ftarget = (const float*)d_in[3];
    float* out = (float*)d_out;

    const size_t ST_FLOATS = (size_t)5 * NB * 2 * NPT;              // state planes
    const size_t NEED = (ST_FLOATS + (size_t)NB * 16 * 16) * 4;     // + partials

    if (ws_size >= NEED) {
        float* stw      = (float*)d_ws;
        float* partials = (float*)d_ws + ST_FLOATS;
        attn_state_kernel<<<dim3(NB, 8, 2), NTHR, 0, stream>>>(target, fsource, ftarget, stw);
        combine_kernel<<<dim3(NB, 16), 128, 0, stream>>>(source, stw, partials);
        svd_finalize_kernel<<<1, 64, 0, stream>>>(partials, out);
    } else {
        float* partials = (float*)d_ws;
        attn_partials_kernel<<<dim3(NB, NJT), NTHR, 0, stream>>>(source, target, fsource, ftarget, partials);
        svd_finalize_kernel<<<1, 64, 0, stream>>>(partials, out);
    }
}